// Round 9
// baseline (233.784 us; speedup 1.0000x reference)
//
#include <hip/hip_runtime.h>
#include <hip/hip_fp16.h>

#define IRR    56
#define EF     48
#define WN     832
#define NEDGE  160000
#define NNODE  8000
#define NT     512                // 8 waves: crew0 (waves 0-3) flavor 0, crew1 (waves 4-7) flavor 1
#define TE2    64                 // edges per block
#define NTASK  (NEDGE / TE2)      // 2500
#define GRID   NTASK

#define INV_SQRT3 0.5773502691896258f
#define INV_SQRT2 0.7071067811865476f
#define A_SCAL    0.22360679774997896f   // 1/sqrt(20)
#define A_VEC     0.20412414523193154f   // 1/sqrt(24)

typedef __bf16 bf16x8 __attribute__((ext_vector_type(8)));
typedef float  f32x4  __attribute__((ext_vector_type(4)));
typedef unsigned short u16x8 __attribute__((ext_vector_type(8)));
typedef unsigned short u16x4 __attribute__((ext_vector_type(4)));

__device__ __forceinline__ unsigned short f2bf(float f) {
    unsigned int u = __builtin_bit_cast(unsigned int, f);
    u += 0x7FFFu + ((u >> 16) & 1u);          // RNE
    return (unsigned short)(u >> 16);
}

// ---- setup: W1T [n][64] + W2L lane-major fragment layout + src histogram ----
// W2L[o]: o = ((i*2+f)*64 + l)*8 + j ; lane l=(q*16+m); value = W2[k= f*32+q*8+j][n= i*16+m]
__global__ void k_setup(const float* __restrict__ w1, const float* __restrict__ b1,
                        const float* __restrict__ w2, const float* __restrict__ b2,
                        unsigned short* __restrict__ W1T, unsigned short* __restrict__ W2L,
                        const int* __restrict__ edge_index, int* __restrict__ hist)
{
    int o = blockIdx.x * 256 + threadIdx.x;
    if (o < 64 * 832) {                       // 53248 elements, coalesced over n
        int k = o / 832;
        int n = o - k * 832;
        float v = (k < EF) ? w2[k * WN + n] : ((k == EF) ? b2[n] : 0.f);
        int i = n >> 4, mm = n & 15;
        int f = k >> 5, q = (k >> 3) & 3, j = k & 7;
        int o2 = (((i * 2 + f) * 64) + (q * 16 + mm)) * 8 + j;
        W2L[o2] = f2bf(v);
    }
    if (o < EF * EF) { int k = o / EF, n = o - k * EF; W1T[n * 64 + k] = f2bf(w1[o]); }
    if (o < EF * 16) { int n = o >> 4, kk = EF + (o & 15); W1T[n * 64 + kk] = (kk == EF) ? f2bf(b1[n]) : (unsigned short)0; }
    if (o < NEDGE) atomicAdd(&hist[edge_index[o]], 1);   // src counts
}

// MFMA pair against the group's H fragments (HB0g/HB1g from enclosing scope)
#define MM2(C, WA, WB) do { \
    C = __builtin_amdgcn_mfma_f32_16x16x32_bf16(__builtin_bit_cast(bf16x8, WA), HB0g, C, 0, 0, 0); \
    C = __builtin_amdgcn_mfma_f32_16x16x32_bf16(__builtin_bit_cast(bf16x8, WB), HB1g, C, 0, 0, 0); \
} while (0)

#define OE_T(WA, WB, FV) do { f32x4 c = {0.f,0.f,0.f,0.f}; MM2(c, WA, WB); float f = (FV); \
    o0 += f*c[0]; o1 += f*c[1]; o2 += f*c[2]; o3 += f*c[3]; } while (0)

#define SA_T(WA, WB, FIDX) do { f32x4 c = {0.f,0.f,0.f,0.f}; MM2(c, WA, WB); float f = Fg[FIDX]; \
    sA[0] += f*c[0]; sA[1] += f*c[1]; sA[2] += f*c[2]; sA[3] += f*c[3]; } while (0)

#define T1_T(WA, WB, U, BASE) do { f32x4 c = {0.f,0.f,0.f,0.f}; MM2(c, WA, WB); \
    _Pragma("unroll") for (int i3 = 0; i3 < 3; i3++) { float f = Fg[(BASE) + (U)*3 + i3]; \
    _Pragma("unroll") for (int r = 0; r < 4; r++) t1[i3*4 + r] += f*c[r]; } } while (0)

#define RED16() do { \
    _Pragma("unroll") for (int r = 0; r < 4; r++) { sA[r] += __shfl_xor(sA[r], 16, 64); sA[r] += __shfl_xor(sA[r], 32, 64); } \
    _Pragma("unroll") for (int i = 0; i < 12; i++) { t1[i] += __shfl_xor(t1[i], 16, 64); t1[i] += __shfl_xor(t1[i], 32, 64); } \
} while (0)

// Weights-stationary GEMM2: each wave holds 6-7 W2 tiles in NAMED registers (primed
// at kernel top; latency hidden under phases A-D) and streams all 4 edge-groups' H
// from LDS. W2 L2 traffic 3.7x lower, zero loads in the GEMM2 dependency chain.
// Tile split per crew: f0: wl0:0-6 wl1:7-13 wl2:14-19 wl3(special):20-25
//                      f1: wl0(special):0-5 wl1:6-12 wl2:13-19 wl3:20-25
// oe/oo partials (3 waves) combine via ds_add_f32 into sO; sA/t1 paths single-wave.
__global__ __launch_bounds__(NT, 2) void tp_fused(
    const float* __restrict__ node_attr,
    const float* __restrict__ edge_attr,
    const float* __restrict__ edge_sh,
    const int*   __restrict__ edge_index,
    const int*   __restrict__ hist,
    const unsigned short* __restrict__ W1T,
    const unsigned short* __restrict__ W2L,
    float* __restrict__ out)
{
    __shared__ __align__(16) float sG[TE2 * 56];               // 14336 B gathered node rows
    __shared__ __align__(16) unsigned short sH[TE2 * 72];      // 9216 B  H (bf16), stride 72
    __shared__ __align__(16) float sF0[TE2 * 61];              // 15616 B flavor-0 features
    __shared__ __align__(16) float sF1[TE2 * 61];              // 15616 B flavor-1 features
    __shared__ __align__(16) float sO[TE2 * IRR];              // 14336 B output staging
    __shared__ __align__(16) float4 sS1v[TE2];                 // 1024 B per-edge (s0,sx,sy,sz)
    __shared__ int   sSrc[TE2], sDst[TE2];
    __shared__ float sInv[TE2];
    // total 70912 B -> 2 blocks/CU

    const int tid   = threadIdx.x;
    const int lane  = tid & 63;
    const int wv    = tid >> 6;                  // 0..7
    const int half  = wv >> 2;                   // crew: 0 -> flavor 0, 1 -> flavor 1
    const int wl    = wv & 3;                    // wave within crew
    const int m     = lane & 15;
    const int quad  = lane >> 4;
    const int em    = wl * 16 + m;               // this lane's own edge (gather/F/GEMM1)
    const int e0    = blockIdx.x * TE2;

    // ---- tile assignment + prime W2 tiles into NAMED registers (fire early) ----
    const unsigned short* Wt = W2L + (size_t)half * 26 * 1024;
    int tb, tn7, special;
    if (half == 0) { tb = (wl == 0) ? 0 : (wl == 1) ? 7 : (wl == 2) ? 14 : 20; tn7 = (wl < 2); special = (wl == 3); }
    else           { tb = (wl == 0) ? 0 : (wl == 1) ? 6 : (wl == 2) ? 13 : 20; tn7 = (wl == 1 || wl == 2); special = (wl == 0); }
    const unsigned short* Wp = Wt + tb * 1024 + lane * 8;
    const int o6 = (tn7 ? 6 : 5) * 1024;
    u16x8 w0A = *(const u16x8*)&Wp[0];        u16x8 w0B = *(const u16x8*)&Wp[512];
    u16x8 w1A = *(const u16x8*)&Wp[1024];     u16x8 w1B = *(const u16x8*)&Wp[1024 + 512];
    u16x8 w2A = *(const u16x8*)&Wp[2048];     u16x8 w2B = *(const u16x8*)&Wp[2048 + 512];
    u16x8 w3A = *(const u16x8*)&Wp[3072];     u16x8 w3B = *(const u16x8*)&Wp[3072 + 512];
    u16x8 w4A = *(const u16x8*)&Wp[4096];     u16x8 w4B = *(const u16x8*)&Wp[4096 + 512];
    u16x8 w5A = *(const u16x8*)&Wp[5120];     u16x8 w5B = *(const u16x8*)&Wp[5120 + 512];
    u16x8 w6A = *(const u16x8*)&Wp[o6];       u16x8 w6B = *(const u16x8*)&Wp[o6 + 512];

    // ---- zero sO (3584 = 7*512) ----
    #pragma unroll
    for (int it = 0; it < 7; it++) sO[it * NT + tid] = 0.f;

    if (tid < TE2)          sSrc[tid]       = edge_index[e0 + tid];
    else if (tid < 2 * TE2) sDst[tid - TE2] = edge_index[NEDGE + e0 + tid - TE2];
    __syncthreads();   // (A) sSrc/sDst + sO zero visible

    // ---- gather node rows: split across all 8 waves ----
    {
        const float* nrow = node_attr + (size_t)sDst[em] * IRR;
        float* g = sG + em * 56;
        if (half == 0) {
            *(float4*)(g + quad * 4)        = *(const float4*)(nrow + quad * 4);
            *(float4*)(g + (quad + 4) * 4)  = *(const float4*)(nrow + (quad + 4) * 4);
        } else {
            *(float4*)(g + (quad + 8) * 4)  = *(const float4*)(nrow + (quad + 8) * 4);
            if (quad < 2) { int c = 12 + quad; *(float4*)(g + c * 4) = *(const float4*)(nrow + c * 4); }
        }
    }
    if (tid >= 256 && tid < 256 + TE2) {         // crew1 wave 0 computes inv counts
        int e = tid - 256;
        sInv[e] = 1.0f / fmaxf((float)hist[sSrc[e]], 1.0f);
    }

    // edge_sh per lane for own edge; crew0 quad0 publishes to sS1v for GEMM2 use
    float4 sh4 = *(const float4*)&edge_sh[(size_t)(e0 + em) * 4];
    const float s0 = sh4.x, sx = sh4.y, sy = sh4.z, sz = sh4.w;
    if (half == 0 && quad == 0) sS1v[em] = sh4;

    __syncthreads();   // (B) sG + sS1v complete

    // ---- F features in f32 (own edge rows, wave-local) ----
    {
        const float* x = sG + em * 56;
        const float c0S = s0 * A_SCAL;
        const float c0V = s0 * A_VEC;
        const float cD3 = INV_SQRT3 * A_SCAL;
        const float cC2 = INV_SQRT2 * A_VEC;
        if (half == 0) {
            float* F = sF0 + em * 61;
            #pragma unroll
            for (int t = 0; t < 4; t++) {
                int u = quad * 4 + t;
                float x0e = x[u];
                F[u]      = x0e * c0S;    // wA0
                F[20 + u] = x0e * A_VEC;  // wA1
            }
            {
                int u = quad;
                float a0 = x[16 + u*3], a1 = x[16 + u*3 + 1], a2 = x[16 + u*3 + 2]; // x1o
                float b0 = x[28 + u*3], b1 = x[28 + u*3 + 1], b2 = x[28 + u*3 + 2]; // x1e
                F[16 + u] = (a0*sx + a1*sy + a2*sz) * cD3;        // wB0 dot_b
                F[36 + u*3 + 0] = a0 * c0V;                       // wB1
                F[36 + u*3 + 1] = a1 * c0V;
                F[36 + u*3 + 2] = a2 * c0V;
                F[48 + u*3 + 0] = (b1*sz - b2*sy) * cC2;          // wC1 cross(x1e,s1)
                F[48 + u*3 + 1] = (b2*sx - b0*sz) * cC2;
                F[48 + u*3 + 2] = (b0*sy - b1*sx) * cC2;
            }
        } else {
            float* F = sF1 + em * 61;
            {
                int u = quad;
                float a0 = x[16 + u*3], a1 = x[16 + u*3 + 1], a2 = x[16 + u*3 + 2]; // x1o
                float b0 = x[28 + u*3], b1 = x[28 + u*3 + 1], b2 = x[28 + u*3 + 2]; // x1e
                F[u*3 + 0]      = (a1*sz - a2*sy) * cC2;          // wB1e cross(x1o,s1)
                F[u*3 + 1]      = (a2*sx - a0*sz) * cC2;
                F[u*3 + 2]      = (a0*sy - a1*sx) * cC2;
                F[12 + u*3 + 0] = b0 * c0V;                       // wC1e
                F[12 + u*3 + 1] = b1 * c0V;
                F[12 + u*3 + 2] = b2 * c0V;
                F[40 + u]       = (b0*sx + b1*sy + b2*sz) * cD3;  // wC0o dot_c
            }
            #pragma unroll
            for (int t = 0; t < 4; t++) {
                int u = quad * 4 + t;
                float x0o = x[40 + u];
                F[24 + u] = x0o * A_VEC;  // wD1e
                F[44 + u] = x0o * c0S;    // wD0o
            }
        }
    }

    // ---- crew0: edge_attr -> bf16 regs + GEMM1 (sH separate buffer, no overlay) ----
    if (half == 0) {
        const float* arow = edge_attr + (size_t)(e0 + em) * EF;
        float av0[8], av1[8];
        {
            float4 p0 = *(const float4*)(arow + quad * 8);
            float4 p1 = *(const float4*)(arow + quad * 8 + 4);
            av0[0]=p0.x; av0[1]=p0.y; av0[2]=p0.z; av0[3]=p0.w;
            av0[4]=p1.x; av0[5]=p1.y; av0[6]=p1.z; av0[7]=p1.w;
        }
        if (quad < 2) {
            float4 p0 = *(const float4*)(arow + 32 + quad * 8);
            float4 p1 = *(const float4*)(arow + 32 + quad * 8 + 4);
            av1[0]=p0.x; av1[1]=p0.y; av1[2]=p0.z; av1[3]=p0.w;
            av1[4]=p1.x; av1[5]=p1.y; av1[6]=p1.z; av1[7]=p1.w;
        } else {
            #pragma unroll
            for (int j = 0; j < 8; j++) av1[j] = 0.f;
            if (quad == 2) av1[0] = 1.f;           // bias row k=48
        }
        u16x8 ub0, ub1;
        #pragma unroll
        for (int j = 0; j < 8; j++) { ub0[j] = f2bf(av0[j]); ub1[j] = f2bf(av1[j]); }
        bf16x8 hb0 = __builtin_bit_cast(bf16x8, ub0);
        bf16x8 hb1 = __builtin_bit_cast(bf16x8, ub1);

        #pragma unroll
        for (int nth = 0; nth < 3; nth++) {
            bf16x8 a0 = __builtin_bit_cast(bf16x8, *(const u16x8*)&W1T[(nth*16 + m)*64 + quad*8]);
            bf16x8 a1 = __builtin_bit_cast(bf16x8, *(const u16x8*)&W1T[(nth*16 + m)*64 + 32 + quad*8]);
            f32x4 c = {0.f, 0.f, 0.f, 0.f};
            c = __builtin_amdgcn_mfma_f32_16x16x32_bf16(a0, hb0, c, 0, 0, 0);
            c = __builtin_amdgcn_mfma_f32_16x16x32_bf16(a1, hb1, c, 0, 0, 0);
            u16x4 hp;
            #pragma unroll
            for (int r = 0; r < 4; r++) hp[r] = f2bf(fmaxf(c[r], 0.f));
            *(u16x4*)&sH[em * 72 + nth*16 + quad*4] = hp;
        }
        if (quad == 3) {
            u16x4 b = {0x3F80, 0, 0, 0}, z = {0, 0, 0, 0};
            *(u16x4*)&sH[em * 72 + 48] = b;
            *(u16x4*)&sH[em * 72 + 52] = z;
            *(u16x4*)&sH[em * 72 + 56] = z;
            *(u16x4*)&sH[em * 72 + 60] = z;
        }
    }
    __syncthreads();   // (D) sH + all sF visible

    // ---- GEMM2 weights-stationary: this wave's tiles x all 4 edge groups ----
    const float* sFme = (half == 0) ? sF0 : sF1;
    const int fb  = (half == 0) ? tb : tb + 34;   // oo: Fg[40 + (i-6)] = Fg[tb+34+t]
    const int chb = (half == 0) ? 0 : 40;

    if (!special) {
        #pragma unroll
        for (int g = 0; g < 4; g++) {
            const int eg = g * 16 + m;
            bf16x8 HB0g = __builtin_bit_cast(bf16x8, *(const u16x8*)&sH[eg * 72 + quad*8]);
            bf16x8 HB1g = __builtin_bit_cast(bf16x8, *(const u16x8*)&sH[eg * 72 + 32 + quad*8]);
            const float* Fg = sFme + eg * 61;
            float o0 = 0.f, o1 = 0.f, o2 = 0.f, o3 = 0.f;
            OE_T(w0A, w0B, Fg[fb + 0]);
            OE_T(w1A, w1B, Fg[fb + 1]);
            OE_T(w2A, w2B, Fg[fb + 2]);
            OE_T(w3A, w3B, Fg[fb + 3]);
            OE_T(w4A, w4B, Fg[fb + 4]);
            OE_T(w5A, w5B, Fg[fb + 5]);
            OE_T(w6A, w6B, tn7 ? Fg[fb + 6] : 0.f);
            float* p = sO + eg * IRR + chb + quad * 4;
            atomicAdd(p + 0, o0); atomicAdd(p + 1, o1);
            atomicAdd(p + 2, o2); atomicAdd(p + 3, o3);
        }
    } else if (half == 0) {
        // wl3 flavor0: tiles 20..23 -> sA (o1o dir term), 24,25 -> t1
        #pragma unroll
        for (int g = 0; g < 4; g++) {
            const int eg = g * 16 + m;
            bf16x8 HB0g = __builtin_bit_cast(bf16x8, *(const u16x8*)&sH[eg * 72 + quad*8]);
            bf16x8 HB1g = __builtin_bit_cast(bf16x8, *(const u16x8*)&sH[eg * 72 + 32 + quad*8]);
            const float* Fg = sFme + eg * 61;
            float sA[4] = {0.f,0.f,0.f,0.f};
            float t1[12] = {0.f,0.f,0.f,0.f,0.f,0.f,0.f,0.f,0.f,0.f,0.f,0.f};
            SA_T(w0A, w0B, 20 + 0*4 + quad);
            SA_T(w1A, w1B, 20 + 1*4 + quad);
            SA_T(w2A, w2B, 20 + 2*4 + quad);
            SA_T(w3A, w3B, 20 + 3*4 + quad);
            T1_T(w4A, w4B, quad, 36);
            T1_T(w5A, w5B, 4 + quad, 36);
            RED16();
            float4 s1g = sS1v[eg];
            if (quad == 0) {
                #pragma unroll
                for (int r = 0; r < 4; r++) {
                    sO[eg * IRR + 16 + r*3 + 0] = sA[r] * s1g.y + t1[0*4 + r];
                    sO[eg * IRR + 16 + r*3 + 1] = sA[r] * s1g.z + t1[1*4 + r];
                    sO[eg * IRR + 16 + r*3 + 2] = sA[r] * s1g.w + t1[2*4 + r];
                }
            }
        }
    } else {
        // wl0 flavor1: tiles 0,1 -> t1 (o1e cross), 2..5 -> sA (=sD, o1e dir term)
        #pragma unroll
        for (int g = 0; g < 4; g++) {
            const int eg = g * 16 + m;
            bf16x8 HB0g = __builtin_bit_cast(bf16x8, *(const u16x8*)&sH[eg * 72 + quad*8]);
            bf16x8 HB1g = __builtin_bit_cast(bf16x8, *(const u16x8*)&sH[eg * 72 + 32 + quad*8]);
            const float* Fg = sFme + eg * 61;
            float sA[4] = {0.f,0.f,0.f,0.f};
            float t1[12] = {0.f,0.f,0.f,0.f,0.f,0.f,0.f,0.f,0.f,0.f,0.f,0.f};
            T1_T(w0A, w0B, quad, 0);
            T1_T(w1A, w1B, 4 + quad, 0);
            SA_T(w2A, w2B, 24 + 0*4 + quad);
            SA_T(w3A, w3B, 24 + 1*4 + quad);
            SA_T(w4A, w4B, 24 + 2*4 + quad);
            SA_T(w5A, w5B, 24 + 3*4 + quad);
            RED16();
            float4 s1g = sS1v[eg];
            if (quad == 0) {
                #pragma unroll
                for (int r = 0; r < 4; r++) {
                    sO[eg * IRR + 28 + r*3 + 0] = sA[r] * s1g.y + t1[0*4 + r];
                    sO[eg * IRR + 28 + r*3 + 1] = sA[r] * s1g.z + t1[1*4 + r];
                    sO[eg * IRR + 28 + r*3 + 2] = sA[r] * s1g.w + t1[2*4 + r];
                }
            }
        }
    }

    __syncthreads();   // (E) sO complete block-wide

    // ---- pre-scaled atomic scatter: full contiguous 224 B rows per edge ----
    #pragma unroll
    for (int it = 0; it < 7; it++) {
        int idx = it * NT + tid;           // < 3584 = 64*56
        int e = idx / IRR, ch = idx - e * IRR;
        unsafeAtomicAdd(&out[(size_t)sSrc[e] * IRR + ch], sO[e * IRR + ch] * sInv[e]);
    }
}

extern "C" void kernel_launch(void* const* d_in, const int* in_sizes, int n_in,
                              void* d_out, int out_size, void* d_ws, size_t ws_size,
                              hipStream_t stream) {
    const float* node_attr  = (const float*)d_in[0];
    const float* edge_attr  = (const float*)d_in[1];
    const float* edge_sh    = (const float*)d_in[2];
    const float* fc_w1      = (const float*)d_in[3];
    const float* fc_b1      = (const float*)d_in[4];
    const float* fc_w2      = (const float*)d_in[5];
    const float* fc_b2      = (const float*)d_in[6];
    const int*   edge_index = (const int*)d_in[7];

    int* hist = (int*)d_ws;                                    // 8000 ints
    unsigned short* W1T = (unsigned short*)(hist + NNODE);     // 48*64
    unsigned short* W2L = W1T + EF * 64;                       // 52*2*64*8 = 53248

    hipMemsetAsync(hist, 0, NNODE * sizeof(int), stream);
    hipMemsetAsync(d_out, 0, (size_t)out_size * sizeof(float), stream);

    k_setup<<<(NEDGE + 255) / 256, 256, 0, stream>>>(
        fc_w1, fc_b1, fc_w2, fc_b2, W1T, W2L, edge_index, hist);

    tp_fused<<<GRID, NT, 0, stream>>>(node_attr, edge_attr, edge_sh, edge_index,
                                      hist, W1T, W2L, (float*)d_out);
}